// Round 1
// baseline (5489.557 us; speedup 1.0000x reference)
//
#include <hip/hip_runtime.h>
#include <cstdint>
#include <cstddef>

// ---------- constants ----------
#define MM 4096
#define NSTEP 50
#define DD 100
#define HID 512
#define K0P 128          // 101 padded to 128
#define SIGC 0.4f
#define RC 0.05f

typedef __bf16 bf16x8 __attribute__((ext_vector_type(8)));
typedef float  f32x4  __attribute__((ext_vector_type(4)));

// ---------- weight prep ----------
// out[n*Kpad + k] = (k < Ksrc) ? in[k*N + n] : 0     (transpose + pad K)
__global__ void k_transpose(const float* __restrict__ in, __bf16* __restrict__ out,
                            int Ksrc, int Kpad, int N) {
    int idx = blockIdx.x * 256 + threadIdx.x;
    if (idx >= N * Kpad) return;
    int n = idx / Kpad, k = idx - n * Kpad;
    out[idx] = (k < Ksrc) ? (__bf16)in[k * N + n] : (__bf16)0.f;
}

// out[r*C + c] = (r < Rsrc) ? in[r*C + c] : 0        (cast + pad rows)
__global__ void k_cast(const float* __restrict__ in, __bf16* __restrict__ out,
                       int Rsrc, int Rpad, int C) {
    int idx = blockIdx.x * 256 + threadIdx.x;
    if (idx >= Rpad * C) return;
    int r = idx / C;
    out[idx] = (r < Rsrc) ? (__bf16)in[idx] : (__bf16)0.f;
}

// ---------- init: X0 = tile(Xi), build tX row [t0, X0, 0-pad] ----------
__global__ __launch_bounds__(256) void k_init(const float* __restrict__ t,
                                              const float* __restrict__ Xi,
                                              float* __restrict__ X0,
                                              __bf16* __restrict__ tX) {
    int m = blockIdx.x * 4 + (threadIdx.x >> 6);
    int lane = threadIdx.x & 63;
    for (int ii = 0; ii < 2; ii++) {
        int d = lane + ii * 64;
        if (d < DD) {
            float x = Xi[d];
            X0[m * DD + d] = x;
            tX[(size_t)m * K0P + 1 + d] = (__bf16)x;
        } else if (d < K0P - 1) {
            tX[(size_t)m * K0P + 1 + d] = (__bf16)0.f;
        }
    }
    if (lane == 0) tX[(size_t)m * K0P] = (__bf16)t[m * (NSTEP + 1)];
}

// ---------- GEMM: C[m][n] = sum_k A[m][k] * Bm[n][k]  (Bm stored N x K) ----------
// EPI 0: v += bias[n]; out0 = sin(v) bf16; out1 = cos(v) bf16   (forward layer)
// EPI 1: v *= cmul[m][n]; out0 = v bf16                          (backward layer)
// EPI 2: if 1 <= n < 101: zOut[m*100 + n-1] = v fp32             (Du extract)
template <int EPI>
__global__ __launch_bounds__(256) void k_gemm(
    const __bf16* __restrict__ A, const __bf16* __restrict__ Bm,
    const float* __restrict__ bias, const __bf16* __restrict__ cmul,
    __bf16* __restrict__ out0, __bf16* __restrict__ out1,
    float* __restrict__ zOut, int K, int Nout) {
    __shared__ __bf16 As[64][40];
    __shared__ __bf16 Bs[64][40];
    int tid = threadIdx.x;
    int rowBlk = blockIdx.y * 64, colBlk = blockIdx.x * 64;
    int srow = tid >> 2, skc = (tid & 3) * 8;
    const __bf16* Ap = A + (size_t)(rowBlk + srow) * K + skc;
    const __bf16* Bp = Bm + (size_t)(colBlk + srow) * K + skc;

    f32x4 acc[2][2] = {};
    int wave = tid >> 6, lane = tid & 63;
    int wr = (wave >> 1) * 32, wc = (wave & 1) * 32;
    int lr = lane & 15, lg = lane >> 4;

    for (int k0 = 0; k0 < K; k0 += 32) {
        __syncthreads();
        uint4 av = *(const uint4*)(Ap + k0);
        uint4 bv = *(const uint4*)(Bp + k0);
        *(uint4*)&As[srow][skc] = av;
        *(uint4*)&Bs[srow][skc] = bv;
        __syncthreads();
        bf16x8 aF0 = *(const bf16x8*)&As[wr + lr][lg * 8];
        bf16x8 aF1 = *(const bf16x8*)&As[wr + 16 + lr][lg * 8];
        bf16x8 bF0 = *(const bf16x8*)&Bs[wc + lr][lg * 8];
        bf16x8 bF1 = *(const bf16x8*)&Bs[wc + 16 + lr][lg * 8];
        acc[0][0] = __builtin_amdgcn_mfma_f32_16x16x32_bf16(aF0, bF0, acc[0][0], 0, 0, 0);
        acc[0][1] = __builtin_amdgcn_mfma_f32_16x16x32_bf16(aF0, bF1, acc[0][1], 0, 0, 0);
        acc[1][0] = __builtin_amdgcn_mfma_f32_16x16x32_bf16(aF1, bF0, acc[1][0], 0, 0, 0);
        acc[1][1] = __builtin_amdgcn_mfma_f32_16x16x32_bf16(aF1, bF1, acc[1][1], 0, 0, 0);
    }

    for (int i = 0; i < 2; i++) {
        for (int j = 0; j < 2; j++) {
            int col = colBlk + wc + j * 16 + lr;
            float bv = (EPI == 0) ? bias[col] : 0.f;
            for (int r = 0; r < 4; r++) {
                int row = rowBlk + wr + i * 16 + lg * 4 + r;
                float v = acc[i][j][r] + bv;
                if (EPI == 0) {
                    float s, c;
                    __sincosf(v, &s, &c);
                    out0[(size_t)row * Nout + col] = (__bf16)s;
                    out1[(size_t)row * Nout + col] = (__bf16)c;
                } else if (EPI == 1) {
                    v *= (float)cmul[(size_t)row * Nout + col];
                    out0[(size_t)row * Nout + col] = (__bf16)v;
                } else {
                    if (col >= 1 && col < 101) zOut[(size_t)row * DD + col - 1] = v;
                }
            }
        }
    }
}

// ---------- u = a4 @ W4 + b4; optional residual accumulate ----------
__global__ __launch_bounds__(256) void k_u(const __bf16* __restrict__ a4,
                                           const float* __restrict__ W4,
                                           const float* __restrict__ b4,
                                           const float* __restrict__ Ytil,
                                           float* __restrict__ Y,
                                           float* __restrict__ acc, int hasResid) {
    int m = blockIdx.x * 4 + (threadIdx.x >> 6);
    int lane = threadIdx.x & 63;
    float p = 0.f;
    for (int k = lane; k < HID; k += 64) p += (float)a4[(size_t)m * HID + k] * W4[k];
    for (int off = 32; off; off >>= 1) p += __shfl_down(p, off);
    __shared__ float red[4];
    if (lane == 0) {
        float u = p + b4[0];
        Y[m] = u;
        float r = 0.f;
        if (hasResid) { float d = u - Ytil[m]; r = d * d; }
        red[threadIdx.x >> 6] = r;
    }
    __syncthreads();
    if (threadIdx.x == 0 && hasResid) atomicAdd(acc, red[0] + red[1] + red[2] + red[3]);
}

// ---------- gz4 = cos(z4) * W4  (elementwise) ----------
__global__ __launch_bounds__(256) void k_gz4(const __bf16* __restrict__ c4,
                                             const float* __restrict__ W4,
                                             __bf16* __restrict__ gz) {
    int idx = blockIdx.x * 256 + threadIdx.x;
    int k = idx & (HID - 1);
    gz[idx] = (__bf16)((float)c4[idx] * W4[k]);
}

// ---------- Euler step n: X1, Ytilde, and next tX ----------
__global__ __launch_bounds__(256) void k_euler(const float* __restrict__ t,
                                               const float* __restrict__ W, int n,
                                               const float* __restrict__ X0,
                                               const float* __restrict__ Y0,
                                               const float* __restrict__ Z0,
                                               float* __restrict__ X1,
                                               float* __restrict__ Ytil,
                                               __bf16* __restrict__ tX) {
    int m = blockIdx.x * 4 + (threadIdx.x >> 6);
    int lane = threadIdx.x & 63;
    float t1v = t[m * (NSTEP + 1) + n];
    float dt = t1v - t[m * (NSTEP + 1) + n - 1];
    float sXZ = 0.f, sZs = 0.f;
    for (int ii = 0; ii < 2; ii++) {
        int d = lane + ii * 64;
        if (d < DD) {
            float x0 = X0[m * DD + d], z0 = Z0[m * DD + d];
            float dW = W[((size_t)m * (NSTEP + 1) + n) * DD + d] -
                       W[((size_t)m * (NSTEP + 1) + n - 1) * DD + d];
            float s = SIGC * x0 * dW;
            sXZ += x0 * z0;
            sZs += z0 * s;
            float x1 = x0 + s;
            X1[m * DD + d] = x1;
            tX[(size_t)m * K0P + 1 + d] = (__bf16)x1;
        } else if (d < K0P - 1) {
            tX[(size_t)m * K0P + 1 + d] = (__bf16)0.f;
        }
    }
    for (int off = 32; off; off >>= 1) {
        sXZ += __shfl_down(sXZ, off);
        sZs += __shfl_down(sZs, off);
    }
    if (lane == 0) {
        float y0 = Y0[m];
        float phi = RC * (y0 - sXZ);
        Ytil[m] = y0 + phi * dt + sZs;
        tX[(size_t)m * K0P] = (__bf16)t1v;
    }
}

// ---------- terminal losses ----------
__global__ __launch_bounds__(256) void k_term(const float* __restrict__ X,
                                              const float* __restrict__ Y,
                                              const float* __restrict__ Z,
                                              float* __restrict__ acc) {
    int m = blockIdx.x * 4 + (threadIdx.x >> 6);
    int lane = threadIdx.x & 63;
    float gX = 0.f, sD = 0.f;
    for (int ii = 0; ii < 2; ii++) {
        int d = lane + ii * 64;
        if (d < DD) {
            float x = X[m * DD + d], z = Z[m * DD + d];
            gX += x * x;
            float e = z - 2.f * x;
            sD += e * e;
        }
    }
    for (int off = 32; off; off >>= 1) {
        gX += __shfl_down(gX, off);
        sD += __shfl_down(sD, off);
    }
    __shared__ float red[4];
    if (lane == 0) {
        float e = Y[m] - gX;
        red[threadIdx.x >> 6] = e * e + sD;
    }
    __syncthreads();
    if (threadIdx.x == 0) atomicAdd(acc, red[0] + red[1] + red[2] + red[3]);
}

__global__ void k_final(const float* __restrict__ acc, float* __restrict__ out) {
    out[0] = acc[0] / (float)MM;
}

// ---------- host ----------
extern "C" void kernel_launch(void* const* d_in, const int* in_sizes, int n_in,
                              void* d_out, int out_size, void* d_ws, size_t ws_size,
                              hipStream_t stream) {
    const float* t  = (const float*)d_in[0];
    const float* W  = (const float*)d_in[1];
    const float* Xi = (const float*)d_in[2];
    const float* Wm[5];
    const float* bb[5];
    for (int i = 0; i < 5; i++) {
        Wm[i] = (const float*)d_in[3 + 2 * i];
        bb[i] = (const float*)d_in[4 + 2 * i];
    }

    char* p = (char*)d_ws;
    auto alloc = [&](size_t bytes) -> void* {
        void* r = (void*)p;
        p += (bytes + 255) & ~(size_t)255;
        return r;
    };

    __bf16* wt[4];
    wt[0] = (__bf16*)alloc((size_t)HID * K0P * 2);
    for (int i = 1; i < 4; i++) wt[i] = (__bf16*)alloc((size_t)HID * HID * 2);
    __bf16* wd[4];
    wd[0] = (__bf16*)alloc((size_t)K0P * HID * 2);
    for (int i = 1; i < 4; i++) wd[i] = (__bf16*)alloc((size_t)HID * HID * 2);
    __bf16* tX = (__bf16*)alloc((size_t)MM * K0P * 2);
    __bf16 *a[4], *c[4];
    for (int i = 0; i < 4; i++) a[i] = (__bf16*)alloc((size_t)MM * HID * 2);
    for (int i = 0; i < 4; i++) c[i] = (__bf16*)alloc((size_t)MM * HID * 2);
    __bf16* gza = (__bf16*)alloc((size_t)MM * HID * 2);
    __bf16* gzb = (__bf16*)alloc((size_t)MM * HID * 2);
    float* X[2];
    float* Z[2];
    float* Y[2];
    for (int i = 0; i < 2; i++) X[i] = (float*)alloc((size_t)MM * DD * 4);
    for (int i = 0; i < 2; i++) Z[i] = (float*)alloc((size_t)MM * DD * 4);
    for (int i = 0; i < 2; i++) Y[i] = (float*)alloc((size_t)MM * 4);
    float* Ytil = (float*)alloc((size_t)MM * 4);
    float* acc = (float*)alloc(256);

    hipMemsetAsync(acc, 0, 256, stream);

    // weight prep
    k_transpose<<<(HID * K0P + 255) / 256, 256, 0, stream>>>(Wm[0], wt[0], 101, K0P, HID);
    for (int i = 1; i < 4; i++)
        k_transpose<<<(HID * HID + 255) / 256, 256, 0, stream>>>(Wm[i], wt[i], HID, HID, HID);
    k_cast<<<(K0P * HID + 255) / 256, 256, 0, stream>>>(Wm[0], wd[0], 101, K0P, HID);
    for (int i = 1; i < 4; i++)
        k_cast<<<(HID * HID + 255) / 256, 256, 0, stream>>>(Wm[i], wd[i], HID, HID, HID);

    k_init<<<MM / 4, 256, 0, stream>>>(t, Xi, X[0], tX);

    dim3 g8(HID / 64, MM / 64);
    dim3 g2(K0P / 64, MM / 64);

    auto evalnet = [&](int slot, int hasResid) {
        k_gemm<0><<<g8, 256, 0, stream>>>(tX, wt[0], bb[0], nullptr, a[0], c[0], nullptr, K0P, HID);
        k_gemm<0><<<g8, 256, 0, stream>>>(a[0], wt[1], bb[1], nullptr, a[1], c[1], nullptr, HID, HID);
        k_gemm<0><<<g8, 256, 0, stream>>>(a[1], wt[2], bb[2], nullptr, a[2], c[2], nullptr, HID, HID);
        k_gemm<0><<<g8, 256, 0, stream>>>(a[2], wt[3], bb[3], nullptr, a[3], c[3], nullptr, HID, HID);
        k_u<<<MM / 4, 256, 0, stream>>>(a[3], Wm[4], bb[4], Ytil, Y[slot], acc, hasResid);
        k_gz4<<<(MM * HID) / 256, 256, 0, stream>>>(c[3], Wm[4], gza);
        k_gemm<1><<<g8, 256, 0, stream>>>(gza, wd[3], nullptr, c[2], gzb, nullptr, nullptr, HID, HID);
        k_gemm<1><<<g8, 256, 0, stream>>>(gzb, wd[2], nullptr, c[1], gza, nullptr, nullptr, HID, HID);
        k_gemm<1><<<g8, 256, 0, stream>>>(gza, wd[1], nullptr, c[0], gzb, nullptr, nullptr, HID, HID);
        k_gemm<2><<<g2, 256, 0, stream>>>(gzb, wd[0], nullptr, nullptr, nullptr, nullptr, Z[slot], HID, K0P);
    };

    evalnet(0, 0);
    for (int n = 1; n <= NSTEP; n++) {
        int o = (n - 1) & 1, s = n & 1;
        k_euler<<<MM / 4, 256, 0, stream>>>(t, W, n, X[o], Y[o], Z[o], X[s], Ytil, tX);
        evalnet(s, 1);
    }
    int fs = NSTEP & 1;
    k_term<<<MM / 4, 256, 0, stream>>>(X[fs], Y[fs], Z[fs], acc);
    k_final<<<1, 1, 0, stream>>>(acc, (float*)d_out);
}

// Round 2
// 5295.687 us; speedup vs baseline: 1.0366x; 1.0366x over previous
//
#include <hip/hip_runtime.h>
#include <cstdint>
#include <cstddef>

// ---------- constants ----------
#define MM 4096
#define NSTEP 50
#define DD 100
#define HID 512
#define K0P 128          // 101 padded to 128
#define SIGC 0.4f
#define RC 0.05f

typedef __bf16 bf16x8 __attribute__((ext_vector_type(8)));
typedef float  f32x4  __attribute__((ext_vector_type(4)));

typedef const __attribute__((address_space(1))) void* gvp;
typedef __attribute__((address_space(3))) void* lvp;

static __device__ __forceinline__ void load_lds16(const void* g, void* l) {
    __builtin_amdgcn_global_load_lds((gvp)g, (lvp)l, 16, 0, 0);
}

// ---------- weight prep ----------
__global__ void k_transpose(const float* __restrict__ in, __bf16* __restrict__ out,
                            int Ksrc, int Kpad, int N) {
    int idx = blockIdx.x * 256 + threadIdx.x;
    if (idx >= N * Kpad) return;
    int n = idx / Kpad, k = idx - n * Kpad;
    out[idx] = (k < Ksrc) ? (__bf16)in[k * N + n] : (__bf16)0.f;
}

__global__ void k_cast(const float* __restrict__ in, __bf16* __restrict__ out,
                       int Rsrc, int Rpad, int C) {
    int idx = blockIdx.x * 256 + threadIdx.x;
    if (idx >= Rpad * C) return;
    int r = idx / C;
    out[idx] = (r < Rsrc) ? (__bf16)in[idx] : (__bf16)0.f;
}

// ---------- init: X0 = tile(Xi), tX row [t0, X0, 0-pad], Y = b4 ----------
__global__ __launch_bounds__(256) void k_init(const float* __restrict__ t,
                                              const float* __restrict__ Xi,
                                              const float* __restrict__ b4,
                                              float* __restrict__ X0,
                                              float* __restrict__ Y,
                                              __bf16* __restrict__ tX) {
    int m = blockIdx.x * 4 + (threadIdx.x >> 6);
    int lane = threadIdx.x & 63;
    for (int ii = 0; ii < 2; ii++) {
        int d = lane + ii * 64;
        if (d < DD) {
            float x = Xi[d];
            X0[m * DD + d] = x;
            tX[(size_t)m * K0P + 1 + d] = (__bf16)x;
        } else if (d < K0P - 1) {
            tX[(size_t)m * K0P + 1 + d] = (__bf16)0.f;
        }
    }
    if (lane == 0) {
        tX[(size_t)m * K0P] = (__bf16)t[m * (NSTEP + 1)];
        Y[m] = b4[0];
    }
}

// ---------- unified GEMM: C[m][n] = sum_k A[m][k]*Bm[n][k] ----------
// BM=64, BN=128, BK=64, 256 threads, 4 waves (2x2), wave tile 32x64.
// LDS XOR-swizzle: physical 16B chunk p at row r holds global chunk p^(r&7).
// EPI 0: fwd layer: v+=bias; out0=sin(v), out1=cos(v)            (bf16)
// EPI 1: bwd layer: v*=cmul; out0=v                               (bf16)
// EPI 2: fwd L3: v+=bias; out0=cos(v)*W4[col]; Y[m] += sin(v)*W4 (atomic)
// EPI 3: bwd L0 + Euler/terminal fused (no global out)
template <int EPI>
__global__ __launch_bounds__(256) void k_gemm(
    const __bf16* __restrict__ A, const __bf16* __restrict__ Bm,
    const float* __restrict__ bias, const __bf16* __restrict__ cmul,
    __bf16* __restrict__ out0, __bf16* __restrict__ out1,
    const float* __restrict__ W4, float* __restrict__ Y,
    const float* __restrict__ t, const float* __restrict__ Wb,
    float* __restrict__ X, float* __restrict__ Ytil,
    __bf16* __restrict__ tXout, const float* __restrict__ b4,
    float* __restrict__ acc, int n, int K, int Nout) {

    __shared__ __align__(16) char ldsPool[(EPI == 3) ? 33792 : 24576];
    __bf16* As = (__bf16*)ldsPool;            // [64][64] swizzled
    __bf16* Bs = (__bf16*)(ldsPool + 8192);   // [128][64] swizzled

    const int tid = threadIdx.x;
    const int wave = tid >> 6, lane = tid & 63;
    const int lr = lane & 15, lg = lane >> 4;
    const int rowBlk = blockIdx.y * 64;
    const int colBlk = blockIdx.x * 128;
    const int wr = (wave >> 1) * 32;   // wave row base in tile
    const int wc = (wave & 1) * 64;    // wave col base in tile

    f32x4 acc4[2][4] = {};

    // staging precompute (A: 2 issues, B: 4 issues of 16B/thread)
    int aRow[2], aG[2], bRow[4], bG[4];
    for (int it = 0; it < 2; it++) {
        int chunk = it * 256 + tid;
        aRow[it] = chunk >> 3;
        aG[it] = (chunk & 7) ^ (aRow[it] & 7);
    }
    for (int it = 0; it < 4; it++) {
        int chunk = it * 256 + tid;
        bRow[it] = chunk >> 3;
        bG[it] = (chunk & 7) ^ (bRow[it] & 7);
    }

    for (int k0 = 0; k0 < K; k0 += 64) {
        __syncthreads();
        #pragma unroll
        for (int it = 0; it < 2; it++)
            load_lds16(A + (size_t)(rowBlk + aRow[it]) * K + k0 + aG[it] * 8,
                       (char*)As + it * 4096 + wave * 1024);
        #pragma unroll
        for (int it = 0; it < 4; it++)
            load_lds16(Bm + (size_t)(colBlk + bRow[it]) * K + k0 + bG[it] * 8,
                       (char*)Bs + it * 4096 + wave * 1024);
        __syncthreads();
        #pragma unroll
        for (int ks = 0; ks < 2; ks++) {
            bf16x8 aF[2], bF[4];
            #pragma unroll
            for (int mi = 0; mi < 2; mi++) {
                int row = wr + mi * 16 + lr;
                int p = (ks * 4 + lg) ^ (row & 7);
                aF[mi] = *(const bf16x8*)((const char*)As + row * 128 + p * 16);
            }
            #pragma unroll
            for (int nj = 0; nj < 4; nj++) {
                int row = wc + nj * 16 + lr;
                int p = (ks * 4 + lg) ^ (row & 7);
                bF[nj] = *(const bf16x8*)((const char*)Bs + row * 128 + p * 16);
            }
            #pragma unroll
            for (int mi = 0; mi < 2; mi++)
                #pragma unroll
                for (int nj = 0; nj < 4; nj++)
                    acc4[mi][nj] = __builtin_amdgcn_mfma_f32_16x16x32_bf16(
                        aF[mi], bF[nj], acc4[mi][nj], 0, 0, 0);
        }
    }

    if (EPI == 0) {
        #pragma unroll
        for (int nj = 0; nj < 4; nj++) {
            int col = colBlk + wc + nj * 16 + lr;
            float bv = bias[col];
            #pragma unroll
            for (int mi = 0; mi < 2; mi++)
                #pragma unroll
                for (int r = 0; r < 4; r++) {
                    int row = rowBlk + wr + mi * 16 + lg * 4 + r;
                    float v = acc4[mi][nj][r] + bv;
                    float s, c;
                    __sincosf(v, &s, &c);
                    out0[(size_t)row * Nout + col] = (__bf16)s;
                    out1[(size_t)row * Nout + col] = (__bf16)c;
                }
        }
    } else if (EPI == 1) {
        #pragma unroll
        for (int nj = 0; nj < 4; nj++) {
            int col = colBlk + wc + nj * 16 + lr;
            #pragma unroll
            for (int mi = 0; mi < 2; mi++)
                #pragma unroll
                for (int r = 0; r < 4; r++) {
                    int row = rowBlk + wr + mi * 16 + lg * 4 + r;
                    float v = acc4[mi][nj][r] * (float)cmul[(size_t)row * Nout + col];
                    out0[(size_t)row * Nout + col] = (__bf16)v;
                }
        }
    } else if (EPI == 2) {
        float ysum[2][4] = {};
        #pragma unroll
        for (int nj = 0; nj < 4; nj++) {
            int col = colBlk + wc + nj * 16 + lr;
            float bv = bias[col];
            float w4 = W4[col];
            #pragma unroll
            for (int mi = 0; mi < 2; mi++)
                #pragma unroll
                for (int r = 0; r < 4; r++) {
                    int row = rowBlk + wr + mi * 16 + lg * 4 + r;
                    float v = acc4[mi][nj][r] + bv;
                    float s, c;
                    __sincosf(v, &s, &c);
                    out0[(size_t)row * Nout + col] = (__bf16)(c * w4);
                    ysum[mi][r] += s * w4;
                }
        }
        #pragma unroll
        for (int mi = 0; mi < 2; mi++)
            #pragma unroll
            for (int r = 0; r < 4; r++) {
                float v = ysum[mi][r];
                v += __shfl_xor(v, 1);
                v += __shfl_xor(v, 2);
                v += __shfl_xor(v, 4);
                v += __shfl_xor(v, 8);
                if (lr == 0) {
                    int row = rowBlk + wr + mi * 16 + lg * 4 + r;
                    atomicAdd(&Y[row], v);
                }
            }
    } else {  // EPI == 3: stash Z in LDS, fused Euler / terminal
        __syncthreads();
        float* Zs = (float*)ldsPool;   // [64][132]
        #pragma unroll
        for (int nj = 0; nj < 4; nj++) {
            int col = wc + nj * 16 + lr;
            #pragma unroll
            for (int mi = 0; mi < 2; mi++)
                #pragma unroll
                for (int r = 0; r < 4; r++) {
                    int rl = wr + mi * 16 + lg * 4 + r;
                    Zs[rl * 132 + col] = acc4[mi][nj][r];
                }
        }
        __syncthreads();
        float resid = 0.f;
        for (int rl = 0; rl < 16; rl++) {
            int lrow = wave * 16 + rl;
            int grow = rowBlk + lrow;
            float t0v = 0.f, t1v = 0.f;
            if (n < NSTEP) {
                t0v = t[grow * (NSTEP + 1) + n];
                t1v = t[grow * (NSTEP + 1) + n + 1];
            }
            float pXZ = 0.f, pZs = 0.f, gX = 0.f, sD = 0.f;
            #pragma unroll
            for (int ii = 0; ii < 2; ii++) {
                int d = lane + ii * 64;
                if (d < DD) {
                    float x0 = X[grow * DD + d];
                    float z = Zs[lrow * 132 + 1 + d];
                    if (n < NSTEP) {
                        float dWv = Wb[((size_t)grow * (NSTEP + 1) + n + 1) * DD + d] -
                                    Wb[((size_t)grow * (NSTEP + 1) + n) * DD + d];
                        float s = SIGC * x0 * dWv;
                        pXZ += x0 * z;
                        pZs += z * s;
                        float x1 = x0 + s;
                        X[grow * DD + d] = x1;
                        tXout[(size_t)grow * K0P + 1 + d] = (__bf16)x1;
                    } else {
                        gX += x0 * x0;
                        float e = z - 2.f * x0;
                        sD += e * e;
                    }
                }
            }
            for (int off = 32; off; off >>= 1) {
                pXZ += __shfl_down(pXZ, off);
                pZs += __shfl_down(pZs, off);
                gX  += __shfl_down(gX, off);
                sD  += __shfl_down(sD, off);
            }
            if (lane == 0) {
                float y0 = Y[grow];
                if (n >= 1) {
                    float dd = y0 - Ytil[grow];
                    resid += dd * dd;
                }
                if (n < NSTEP) {
                    float phi = RC * (y0 - pXZ);
                    Ytil[grow] = y0 + phi * (t1v - t0v) + pZs;
                    tXout[(size_t)grow * K0P] = (__bf16)t1v;
                    Y[grow] = b4[0];   // init accumulator for next step's fwd L3
                } else {
                    float e = y0 - gX;
                    resid += e * e + sD;
                }
            }
        }
        if (lane == 0) atomicAdd(acc, resid);
    }
}

__global__ void k_final(const float* __restrict__ acc, float* __restrict__ out) {
    out[0] = acc[0] / (float)MM;
}

// ---------- host ----------
extern "C" void kernel_launch(void* const* d_in, const int* in_sizes, int n_in,
                              void* d_out, int out_size, void* d_ws, size_t ws_size,
                              hipStream_t stream) {
    const float* t  = (const float*)d_in[0];
    const float* W  = (const float*)d_in[1];
    const float* Xi = (const float*)d_in[2];
    const float* Wm[5];
    const float* bb[5];
    for (int i = 0; i < 5; i++) {
        Wm[i] = (const float*)d_in[3 + 2 * i];
        bb[i] = (const float*)d_in[4 + 2 * i];
    }

    char* p = (char*)d_ws;
    auto alloc = [&](size_t bytes) -> void* {
        void* r = (void*)p;
        p += (bytes + 255) & ~(size_t)255;
        return r;
    };

    __bf16* wt[4];
    wt[0] = (__bf16*)alloc((size_t)HID * K0P * 2);
    for (int i = 1; i < 4; i++) wt[i] = (__bf16*)alloc((size_t)HID * HID * 2);
    __bf16* wd[4];
    wd[0] = (__bf16*)alloc((size_t)K0P * HID * 2);
    for (int i = 1; i < 4; i++) wd[i] = (__bf16*)alloc((size_t)HID * HID * 2);
    __bf16* tX = (__bf16*)alloc((size_t)MM * K0P * 2);
    __bf16 *a[3], *c[3];
    for (int i = 0; i < 3; i++) a[i] = (__bf16*)alloc((size_t)MM * HID * 2);
    for (int i = 0; i < 3; i++) c[i] = (__bf16*)alloc((size_t)MM * HID * 2);
    __bf16* gza = (__bf16*)alloc((size_t)MM * HID * 2);
    __bf16* gzb = (__bf16*)alloc((size_t)MM * HID * 2);
    float* X    = (float*)alloc((size_t)MM * DD * 4);
    float* Y    = (float*)alloc((size_t)MM * 4);
    float* Ytil = (float*)alloc((size_t)MM * 4);
    float* acc  = (float*)alloc(256);

    hipMemsetAsync(acc, 0, 256, stream);

    // weight prep
    k_transpose<<<(HID * K0P + 255) / 256, 256, 0, stream>>>(Wm[0], wt[0], 101, K0P, HID);
    for (int i = 1; i < 4; i++)
        k_transpose<<<(HID * HID + 255) / 256, 256, 0, stream>>>(Wm[i], wt[i], HID, HID, HID);
    k_cast<<<(K0P * HID + 255) / 256, 256, 0, stream>>>(Wm[0], wd[0], 101, K0P, HID);
    for (int i = 1; i < 4; i++)
        k_cast<<<(HID * HID + 255) / 256, 256, 0, stream>>>(Wm[i], wd[i], HID, HID, HID);

    k_init<<<MM / 4, 256, 0, stream>>>(t, Xi, bb[4], X, Y, tX);

    dim3 gBig(HID / 128, MM / 64);   // (4, 64)
    dim3 gZ(1, MM / 64);             // (1, 64)

    for (int n = 0; n <= NSTEP; n++) {
        // forward
        k_gemm<0><<<gBig, 256, 0, stream>>>(tX, wt[0], bb[0], nullptr, a[0], c[0],
            nullptr, nullptr, nullptr, nullptr, nullptr, nullptr, nullptr, nullptr,
            nullptr, n, K0P, HID);
        k_gemm<0><<<gBig, 256, 0, stream>>>(a[0], wt[1], bb[1], nullptr, a[1], c[1],
            nullptr, nullptr, nullptr, nullptr, nullptr, nullptr, nullptr, nullptr,
            nullptr, n, HID, HID);
        k_gemm<0><<<gBig, 256, 0, stream>>>(a[1], wt[2], bb[2], nullptr, a[2], c[2],
            nullptr, nullptr, nullptr, nullptr, nullptr, nullptr, nullptr, nullptr,
            nullptr, n, HID, HID);
        k_gemm<2><<<gBig, 256, 0, stream>>>(a[2], wt[3], bb[3], nullptr, gza, nullptr,
            Wm[4], Y, nullptr, nullptr, nullptr, nullptr, nullptr, nullptr,
            nullptr, n, HID, HID);
        // backward
        k_gemm<1><<<gBig, 256, 0, stream>>>(gza, wd[3], nullptr, c[2], gzb, nullptr,
            nullptr, nullptr, nullptr, nullptr, nullptr, nullptr, nullptr, nullptr,
            nullptr, n, HID, HID);
        k_gemm<1><<<gBig, 256, 0, stream>>>(gzb, wd[2], nullptr, c[1], gza, nullptr,
            nullptr, nullptr, nullptr, nullptr, nullptr, nullptr, nullptr, nullptr,
            nullptr, n, HID, HID);
        k_gemm<1><<<gBig, 256, 0, stream>>>(gza, wd[1], nullptr, c[0], gzb, nullptr,
            nullptr, nullptr, nullptr, nullptr, nullptr, nullptr, nullptr, nullptr,
            nullptr, n, HID, HID);
        // bwd L0 + Euler(n+1) / terminal
        k_gemm<3><<<gZ, 256, 0, stream>>>(gzb, wd[0], nullptr, nullptr, nullptr, nullptr,
            nullptr, Y, t, W, X, Ytil, tX, bb[4], acc, n, HID, K0P);
    }
    k_final<<<1, 1, 0, stream>>>(acc, (float*)d_out);
}